// Round 3
// baseline (108.479 us; speedup 1.0000x reference)
//
#include <hip/hip_runtime.h>

#define L_MAX 5
#define D_DIM 32

// clang native vector types — required for __builtin_nontemporal_{load,store}
typedef int   vint4   __attribute__((ext_vector_type(4)));
typedef float vfloat4 __attribute__((ext_vector_type(4)));

// Kernel 1: precomp[e*L + l] = dot(edge_vector[l], edge_attr[e])
// edge_attr is read once (16 MB) -> nontemporal; precomp stores stay cached
// (we WANT the 2.6 MB table resident in L2 for kernel 2's gathers).
__global__ __launch_bounds__(256) void precompute_dots_kernel(
        const float* __restrict__ edge_attr,
        const float* __restrict__ edge_vector,
        float* __restrict__ precomp, int E) {
    __shared__ float ev[L_MAX * D_DIM];
    int tid = threadIdx.x;
    if (tid < L_MAX * D_DIM) ev[tid] = edge_vector[tid];
    __syncthreads();

    int e = blockIdx.x * blockDim.x + tid;
    if (e >= E) return;

    const vfloat4* row = (const vfloat4*)(edge_attr + (size_t)e * D_DIM);
    float acc[L_MAX];
#pragma unroll
    for (int l = 0; l < L_MAX; ++l) acc[l] = 0.f;

#pragma unroll
    for (int c4 = 0; c4 < D_DIM / 4; ++c4) {
        vfloat4 a = __builtin_nontemporal_load(row + c4);
#pragma unroll
        for (int l = 0; l < L_MAX; ++l) {
            const float* evl = ev + l * D_DIM + c4 * 4;
            acc[l] += evl[0] * a.x + evl[1] * a.y + evl[2] * a.z + evl[3] * a.w;
        }
    }
#pragma unroll
    for (int l = 0; l < L_MAX; ++l)
        precomp[(size_t)e * L_MAX + l] = acc[l];
}

__device__ __forceinline__ float pair_val(int e0, int e1, int e2, int e3, int e4,
                                          int len, const float* __restrict__ pc) {
    float s = 0.f;
    if (len > 0) s += pc[(size_t)e0 * L_MAX + 0];
    if (len > 1) s += pc[(size_t)e1 * L_MAX + 1];
    if (len > 2) s += pc[(size_t)e2 * L_MAX + 2];
    if (len > 3) s += pc[(size_t)e3 * L_MAX + 3];
    if (len > 4) s += pc[(size_t)e4 * L_MAX + 4];
    return (len > 0) ? s / (float)len : 0.f;
}

// Kernel 2: 4 pairs per thread. Streams (path_edges, path_len, out) are
// nontemporal so they don't evict the precomp gather table from L2.
__global__ __launch_bounds__(256) void path_mean4_kernel(
        const int* __restrict__ path_edges,
        const int* __restrict__ path_len,
        const float* __restrict__ precomp,
        float* __restrict__ out, int P) {
    int t = blockIdx.x * blockDim.x + threadIdx.x;
    int p0 = t * 4;
    if (p0 >= P) return;

    if (p0 + 3 < P) {
        const vint4* pe4 = (const vint4*)path_edges + (size_t)t * 5;
        vint4 a = __builtin_nontemporal_load(pe4 + 0);
        vint4 b = __builtin_nontemporal_load(pe4 + 1);
        vint4 c = __builtin_nontemporal_load(pe4 + 2);
        vint4 d = __builtin_nontemporal_load(pe4 + 3);
        vint4 e = __builtin_nontemporal_load(pe4 + 4);
        vint4 ln = __builtin_nontemporal_load((const vint4*)path_len + t);

        // pair0: a.x a.y a.z a.w b.x   len ln.x
        // pair1: b.y b.z b.w c.x c.y   len ln.y
        // pair2: c.z c.w d.x d.y d.z   len ln.z
        // pair3: d.w e.x e.y e.z e.w   len ln.w
        vfloat4 r;
        r.x = pair_val(a.x, a.y, a.z, a.w, b.x, ln.x, precomp);
        r.y = pair_val(b.y, b.z, b.w, c.x, c.y, ln.y, precomp);
        r.z = pair_val(c.z, c.w, d.x, d.y, d.z, ln.z, precomp);
        r.w = pair_val(d.w, e.x, e.y, e.z, e.w, ln.w, precomp);
        __builtin_nontemporal_store(r, (vfloat4*)out + t);
    } else {
        for (int p = p0; p < P; ++p) {
            const int* pe = path_edges + (size_t)p * L_MAX;
            int len = path_len[p];
            out[p] = pair_val(pe[0], pe[1], pe[2], pe[3], pe[4], len, precomp);
        }
    }
}

// Fallback (ws too small): recompute each hop's dot directly from edge_attr.
__global__ __launch_bounds__(256) void path_mean_direct_kernel(
        const int* __restrict__ path_edges,
        const int* __restrict__ path_len,
        const float* __restrict__ edge_attr,
        const float* __restrict__ edge_vector,
        float* __restrict__ out, int P) {
    __shared__ float ev[L_MAX * D_DIM];
    int tid = threadIdx.x;
    if (tid < L_MAX * D_DIM) ev[tid] = edge_vector[tid];
    __syncthreads();

    int p = blockIdx.x * blockDim.x + tid;
    if (p >= P) return;

    int len = path_len[p];
    const int* pe = path_edges + (size_t)p * L_MAX;

    float s = 0.f;
#pragma unroll
    for (int l = 0; l < L_MAX; ++l) {
        if (l < len) {
            const float4* row = (const float4*)(edge_attr + (size_t)pe[l] * D_DIM);
            float d = 0.f;
#pragma unroll
            for (int c4 = 0; c4 < D_DIM / 4; ++c4) {
                float4 a = row[c4];
                const float* evl = ev + l * D_DIM + c4 * 4;
                d += evl[0] * a.x + evl[1] * a.y + evl[2] * a.z + evl[3] * a.w;
            }
            s += d;
        }
    }
    out[p] = (len > 0) ? s / (float)len : 0.f;
}

extern "C" void kernel_launch(void* const* d_in, const int* in_sizes, int n_in,
                              void* d_out, int out_size, void* d_ws, size_t ws_size,
                              hipStream_t stream) {
    // Inputs: x [N*D] (unused), edge_attr [E*D], edge_vector [L*D],
    // path_edges [P*L] int32, path_len [P] int32.
    const float* edge_attr   = (const float*)d_in[1];
    const float* edge_vector = (const float*)d_in[2];
    const int*   path_edges  = (const int*)d_in[3];
    const int*   path_len    = (const int*)d_in[4];
    float* out = (float*)d_out;

    const int E = in_sizes[1] / D_DIM;
    const int P = in_sizes[4];

    const size_t precomp_bytes = (size_t)E * L_MAX * sizeof(float);

    if (ws_size >= precomp_bytes) {
        float* precomp = (float*)d_ws;
        {
            int block = 256;
            int grid = (E + block - 1) / block;
            precompute_dots_kernel<<<grid, block, 0, stream>>>(edge_attr, edge_vector,
                                                               precomp, E);
        }
        {
            int block = 256;
            int threads = (P + 3) / 4;
            int grid = (threads + block - 1) / block;
            path_mean4_kernel<<<grid, block, 0, stream>>>(path_edges, path_len,
                                                          precomp, out, P);
        }
    } else {
        int block = 256;
        int grid = (P + block - 1) / block;
        path_mean_direct_kernel<<<grid, block, 0, stream>>>(path_edges, path_len,
                                                            edge_attr, edge_vector,
                                                            out, P);
    }
}

// Round 4
// 105.266 us; speedup vs baseline: 1.0305x; 1.0305x over previous
//
#include <hip/hip_runtime.h>

#define L_MAX 5
#define D_DIM 32

// clang native vector types — required for __builtin_nontemporal_{load,store}
typedef int   vint4   __attribute__((ext_vector_type(4)));
typedef float vfloat4 __attribute__((ext_vector_type(4)));

// Kernel 1: precomp[l*E + e] = dot(edge_vector[l], edge_attr[e])
// Transposed [l][E] layout: wave's 5 stores are each perfectly coalesced
// (lane i -> pc[l*E + e0 + i], contiguous dwords, 4 lines/instr vs 20).
// edge_attr is read once (16 MB) -> nontemporal so it doesn't evict the
// precomp table being built in L2.
__global__ __launch_bounds__(256) void precompute_dots_kernel(
        const float* __restrict__ edge_attr,
        const float* __restrict__ edge_vector,
        float* __restrict__ precomp, int E) {
    __shared__ float ev[L_MAX * D_DIM];
    int tid = threadIdx.x;
    if (tid < L_MAX * D_DIM) ev[tid] = edge_vector[tid];
    __syncthreads();

    int e = blockIdx.x * blockDim.x + tid;
    if (e >= E) return;

    const vfloat4* row = (const vfloat4*)(edge_attr + (size_t)e * D_DIM);
    float acc[L_MAX];
#pragma unroll
    for (int l = 0; l < L_MAX; ++l) acc[l] = 0.f;

#pragma unroll
    for (int c4 = 0; c4 < D_DIM / 4; ++c4) {
        vfloat4 a = __builtin_nontemporal_load(row + c4);
#pragma unroll
        for (int l = 0; l < L_MAX; ++l) {
            const float* evl = ev + l * D_DIM + c4 * 4;
            acc[l] += evl[0] * a.x + evl[1] * a.y + evl[2] * a.z + evl[3] * a.w;
        }
    }
#pragma unroll
    for (int l = 0; l < L_MAX; ++l)
        precomp[(size_t)l * E + e] = acc[l];
}

__device__ __forceinline__ float pair_val(int e0, int e1, int e2, int e3, int e4,
                                          int len, const float* __restrict__ pc,
                                          int E) {
    float s = 0.f;
    if (len > 0) s += pc[(size_t)0 * E + e0];
    if (len > 1) s += pc[(size_t)1 * E + e1];
    if (len > 2) s += pc[(size_t)2 * E + e2];
    if (len > 3) s += pc[(size_t)3 * E + e3];
    if (len > 4) s += pc[(size_t)4 * E + e4];
    return (len > 0) ? s / (float)len : 0.f;
}

// Kernel 2: 4 pairs per thread, plain (cached) loads/stores.
__global__ __launch_bounds__(256) void path_mean4_kernel(
        const int* __restrict__ path_edges,
        const int* __restrict__ path_len,
        const float* __restrict__ precomp,
        float* __restrict__ out, int P, int E) {
    int t = blockIdx.x * blockDim.x + threadIdx.x;
    int p0 = t * 4;
    if (p0 >= P) return;

    if (p0 + 3 < P) {
        const vint4* pe4 = (const vint4*)path_edges + (size_t)t * 5;
        vint4 a = pe4[0];
        vint4 b = pe4[1];
        vint4 c = pe4[2];
        vint4 d = pe4[3];
        vint4 e = pe4[4];
        vint4 ln = ((const vint4*)path_len)[t];

        // pair0: a.x a.y a.z a.w b.x   len ln.x
        // pair1: b.y b.z b.w c.x c.y   len ln.y
        // pair2: c.z c.w d.x d.y d.z   len ln.z
        // pair3: d.w e.x e.y e.z e.w   len ln.w
        vfloat4 r;
        r.x = pair_val(a.x, a.y, a.z, a.w, b.x, ln.x, precomp, E);
        r.y = pair_val(b.y, b.z, b.w, c.x, c.y, ln.y, precomp, E);
        r.z = pair_val(c.z, c.w, d.x, d.y, d.z, ln.z, precomp, E);
        r.w = pair_val(d.w, e.x, e.y, e.z, e.w, ln.w, precomp, E);
        ((vfloat4*)out)[t] = r;
    } else {
        for (int p = p0; p < P; ++p) {
            const int* pe = path_edges + (size_t)p * L_MAX;
            int len = path_len[p];
            out[p] = pair_val(pe[0], pe[1], pe[2], pe[3], pe[4], len, precomp, E);
        }
    }
}

// Fallback (ws too small): recompute each hop's dot directly from edge_attr.
__global__ __launch_bounds__(256) void path_mean_direct_kernel(
        const int* __restrict__ path_edges,
        const int* __restrict__ path_len,
        const float* __restrict__ edge_attr,
        const float* __restrict__ edge_vector,
        float* __restrict__ out, int P) {
    __shared__ float ev[L_MAX * D_DIM];
    int tid = threadIdx.x;
    if (tid < L_MAX * D_DIM) ev[tid] = edge_vector[tid];
    __syncthreads();

    int p = blockIdx.x * blockDim.x + tid;
    if (p >= P) return;

    int len = path_len[p];
    const int* pe = path_edges + (size_t)p * L_MAX;

    float s = 0.f;
#pragma unroll
    for (int l = 0; l < L_MAX; ++l) {
        if (l < len) {
            const float4* row = (const float4*)(edge_attr + (size_t)pe[l] * D_DIM);
            float d = 0.f;
#pragma unroll
            for (int c4 = 0; c4 < D_DIM / 4; ++c4) {
                float4 a = row[c4];
                const float* evl = ev + l * D_DIM + c4 * 4;
                d += evl[0] * a.x + evl[1] * a.y + evl[2] * a.z + evl[3] * a.w;
            }
            s += d;
        }
    }
    out[p] = (len > 0) ? s / (float)len : 0.f;
}

extern "C" void kernel_launch(void* const* d_in, const int* in_sizes, int n_in,
                              void* d_out, int out_size, void* d_ws, size_t ws_size,
                              hipStream_t stream) {
    // Inputs: x [N*D] (unused), edge_attr [E*D], edge_vector [L*D],
    // path_edges [P*L] int32, path_len [P] int32.
    const float* edge_attr   = (const float*)d_in[1];
    const float* edge_vector = (const float*)d_in[2];
    const int*   path_edges  = (const int*)d_in[3];
    const int*   path_len    = (const int*)d_in[4];
    float* out = (float*)d_out;

    const int E = in_sizes[1] / D_DIM;
    const int P = in_sizes[4];

    const size_t precomp_bytes = (size_t)E * L_MAX * sizeof(float);

    if (ws_size >= precomp_bytes) {
        float* precomp = (float*)d_ws;
        {
            int block = 256;
            int grid = (E + block - 1) / block;
            precompute_dots_kernel<<<grid, block, 0, stream>>>(edge_attr, edge_vector,
                                                               precomp, E);
        }
        {
            int block = 256;
            int threads = (P + 3) / 4;
            int grid = (threads + block - 1) / block;
            path_mean4_kernel<<<grid, block, 0, stream>>>(path_edges, path_len,
                                                          precomp, out, P, E);
        }
    } else {
        int block = 256;
        int grid = (P + block - 1) / block;
        path_mean_direct_kernel<<<grid, block, 0, stream>>>(path_edges, path_len,
                                                            edge_attr, edge_vector,
                                                            out, P);
    }
}